// Round 1
// baseline (520.792 us; speedup 1.0000x reference)
//
#include <hip/hip_runtime.h>

// Problem constants
#define BB 8
#define CC 128   // channels of x and of u
#define HH 64
#define WW 64
#define NOFF 18  // 2*K offset channels

// ---------------------------------------------------------------------------
// Kernel 0: transpose weight (O=128, C=128, 3, 3) -> wt[kk][c][o]
// so the main kernel's weight rows are contiguous across o.
// ---------------------------------------------------------------------------
__global__ __launch_bounds__(256) void wt_transpose_kernel(
    const float* __restrict__ w, float* __restrict__ wt)
{
    int idx = blockIdx.x * 256 + threadIdx.x;   // dst index (kk*128 + c)*128 + o
    if (idx >= 9 * 128 * 128) return;
    int o  = idx & 127;
    int c  = (idx >> 7) & 127;
    int kk = idx >> 14;
    wt[idx] = w[(o * 128 + c) * 9 + kk];
}

// ---------------------------------------------------------------------------
// Kernel 1: offset conv.  offset[b, oc, h, w] =
//   sum_{ic<256, kh, kw} concat[b, ic, h-1+kh, w-1+kw] * ow[oc, ic, kh, kw] + ob[oc]
// Block = (b,h) row, 256 threads: lane = w, wave = ic-quarter. 18 acc/thread,
// LDS reduce across the 4 waves.
// ---------------------------------------------------------------------------
__global__ __launch_bounds__(256) void offset_conv_kernel(
    const float* __restrict__ x, const float* __restrict__ u,
    const float* __restrict__ ow, const float* __restrict__ ob,
    float* __restrict__ off)
{
    const int h    = blockIdx.x;
    const int b    = blockIdx.y;
    const int lane = threadIdx.x & 63;   // = w
    const int wv   = threadIdx.x >> 6;   // ic block 0..3

    float acc[NOFF];
#pragma unroll
    for (int i = 0; i < NOFF; ++i) acc[i] = 0.f;

    for (int kh = 0; kh < 3; ++kh) {
        int y = h - 1 + kh;
        if (y < 0 || y >= HH) continue;
        for (int icl = 0; icl < 64; ++icl) {
            int ic = wv * 64 + icl;
            const float* src = (ic < CC)
                ? (x + ((size_t)(b * CC + ic) * HH + y) * WW)
                : (u + ((size_t)(b * CC + (ic - CC)) * HH + y) * WW);
            float v0 = (lane >= 1)      ? src[lane - 1] : 0.f;
            float v1 = src[lane];
            float v2 = (lane < WW - 1)  ? src[lane + 1] : 0.f;
            const float* wr = ow + (size_t)ic * 9 + kh * 3;   // + oc*2304 per oc
#pragma unroll
            for (int oc = 0; oc < NOFF; ++oc) {
                const float* wp = wr + (size_t)oc * (256 * 9);
                acc[oc] = fmaf(wp[0], v0, acc[oc]);
                acc[oc] = fmaf(wp[1], v1, acc[oc]);
                acc[oc] = fmaf(wp[2], v2, acc[oc]);
            }
        }
    }

    __shared__ float part[4][NOFF][64];
#pragma unroll
    for (int oc = 0; oc < NOFF; ++oc) part[wv][oc][lane] = acc[oc];
    __syncthreads();

    for (int idx = threadIdx.x; idx < NOFF * 64; idx += 256) {
        int oc = idx >> 6;
        int w2 = idx & 63;
        float s = part[0][oc][w2] + part[1][oc][w2] + part[2][oc][w2] +
                  part[3][oc][w2] + ob[oc];
        off[((size_t)(b * NOFF + oc) * HH + h) * WW + w2] = s;
    }
}

// ---------------------------------------------------------------------------
// Kernel 2: deformable sample + einsum.
// Block = (b,h) row, 256 threads. Per tap k:
//   A) wave0 computes bilinear corner idx/weights per w (validity folded in)
//   B) all threads fill samp[c][w] (128x64 f32 LDS tile) via 4 gathers from u
//   C) each wave accumulates 32 output channels: acc[o] += wt[k][c][o]*samp[c][w]
// ---------------------------------------------------------------------------
__global__ __launch_bounds__(256) void fam_main_kernel(
    const float* __restrict__ u, const float* __restrict__ wt,
    const float* __restrict__ bias, const float* __restrict__ off,
    float* __restrict__ out)
{
    const int h    = blockIdx.x;
    const int b    = blockIdx.y;
    const int tid  = threadIdx.x;
    const int lane = tid & 63;   // = w
    const int wv   = tid >> 6;   // oc quarter

    __shared__ float samp[128][64];
    __shared__ float s_w00[64], s_w01[64], s_w10[64], s_w11[64];
    __shared__ int   s_i00[64], s_i01[64], s_i10[64], s_i11[64];

    float acc[32];
#pragma unroll
    for (int i = 0; i < 32; ++i) acc[i] = 0.f;

    const int oc0 = __builtin_amdgcn_readfirstlane(wv * 32);

    for (int k = 0; k < 9; ++k) {
        if (tid < 64) {
            int wq = tid;
            float dy = off[((size_t)(b * NOFF + 2 * k)     * HH + h) * WW + wq];
            float dx = off[((size_t)(b * NOFF + 2 * k + 1) * HH + h) * WW + wq];
            float py = (float)(h - 1 + k / 3) + dy;
            float px = (float)(wq - 1 + k % 3) + dx;
            float y0f = floorf(py), x0f = floorf(px);
            int y0 = (int)y0f, x0 = (int)x0f;
            float fy = py - y0f, fx = px - x0f;
            float wy0 = 1.f - fy, wy1 = fy, wx0 = 1.f - fx, wx1 = fx;
            bool vy0 = (y0 >= 0)     && (y0 < HH);
            bool vy1 = (y0 + 1 >= 0) && (y0 + 1 < HH);
            bool vx0 = (x0 >= 0)     && (x0 < WW);
            bool vx1 = (x0 + 1 >= 0) && (x0 + 1 < WW);
            int y0c = min(max(y0, 0), HH - 1);
            int y1c = min(max(y0 + 1, 0), HH - 1);
            int x0c = min(max(x0, 0), WW - 1);
            int x1c = min(max(x0 + 1, 0), WW - 1);
            s_w00[wq] = wy0 * wx0 * ((vy0 && vx0) ? 1.f : 0.f);
            s_w01[wq] = wy0 * wx1 * ((vy0 && vx1) ? 1.f : 0.f);
            s_w10[wq] = wy1 * wx0 * ((vy1 && vx0) ? 1.f : 0.f);
            s_w11[wq] = wy1 * wx1 * ((vy1 && vx1) ? 1.f : 0.f);
            s_i00[wq] = y0c * WW + x0c;
            s_i01[wq] = y0c * WW + x1c;
            s_i10[wq] = y1c * WW + x0c;
            s_i11[wq] = y1c * WW + x1c;
        }
        __syncthreads();

        // Phase B: fill samp tile
        {
            float w00 = s_w00[lane], w01 = s_w01[lane];
            float w10 = s_w10[lane], w11 = s_w11[lane];
            int   i00 = s_i00[lane], i01 = s_i01[lane];
            int   i10 = s_i10[lane], i11 = s_i11[lane];
            const float* ub = u + (size_t)b * CC * HH * WW;
#pragma unroll 4
            for (int i = 0; i < 32; ++i) {
                int c = wv * 32 + i;
                const float* up = ub + (size_t)c * (HH * WW);
                float v = w00 * up[i00] + w01 * up[i01] +
                          w10 * up[i10] + w11 * up[i11];
                samp[c][lane] = v;
            }
        }
        __syncthreads();

        // Phase C: acc[o] += wt[k][c][oc0+o] * samp[c][w]
        {
            const float* wk = wt + (size_t)k * 128 * 128 + oc0;
            for (int c = 0; c < 128; ++c) {
                float s = samp[c][lane];
                const float* wrow = wk + (size_t)c * 128;
#pragma unroll
                for (int i = 0; i < 32; ++i)
                    acc[i] = fmaf(wrow[i], s, acc[i]);
            }
        }
        __syncthreads();
    }

    // Epilogue
#pragma unroll
    for (int i = 0; i < 32; ++i) {
        int oc = oc0 + i;
        out[((size_t)(b * CC + oc) * HH + h) * WW + lane] = acc[i] + bias[oc];
    }
}

extern "C" void kernel_launch(void* const* d_in, const int* in_sizes, int n_in,
                              void* d_out, int out_size, void* d_ws, size_t ws_size,
                              hipStream_t stream) {
    const float* x    = (const float*)d_in[0];
    const float* u    = (const float*)d_in[1];
    const float* wgt  = (const float*)d_in[2];
    const float* bias = (const float*)d_in[3];
    const float* ow   = (const float*)d_in[4];
    const float* ob   = (const float*)d_in[5];
    float* out = (float*)d_out;

    float* off = (float*)d_ws;                           // 8*18*64*64 floats
    float* wt  = off + (size_t)BB * NOFF * HH * WW;      // 9*128*128 floats

    hipLaunchKernelGGL(wt_transpose_kernel, dim3(576), dim3(256), 0, stream,
                       wgt, wt);
    hipLaunchKernelGGL(offset_conv_kernel, dim3(HH, BB), dim3(256), 0, stream,
                       x, u, ow, ob, off);
    hipLaunchKernelGGL(fam_main_kernel, dim3(HH, BB), dim3(256), 0, stream,
                       u, wt, bias, off, out);
}

// Round 2
// 380.235 us; speedup vs baseline: 1.3697x; 1.3697x over previous
//
#include <hip/hip_runtime.h>

#define BB 8
#define CC 128
#define HH 64
#define WW 64
#define NOFF 18

typedef __bf16 bf16x8 __attribute__((ext_vector_type(8)));
typedef float  f32x4  __attribute__((ext_vector_type(4)));
typedef float  f32x2u __attribute__((ext_vector_type(2), aligned(4)));

// ---------------------------------------------------------------------------
// Kernel 0: pack weight (O,C,3,3) f32 -> bf16 A-fragments for 16x16x32 MFMA.
// Chunk (k, mt2, ks): lane holds A[o = mt2*16 + (lane&15)][c = ks*32 + (lane>>4)*8 + j]
// flat idx = (((k*8 + mt2)*4 + ks)*64 + lane)*8 + j  -> wave loads = coalesced dwordx4.
// ---------------------------------------------------------------------------
__global__ __launch_bounds__(256) void prep_afrag_kernel(
    const float* __restrict__ w, __bf16* __restrict__ af)
{
    int idx = blockIdx.x * 256 + threadIdx.x;
    if (idx >= 9 * 8 * 4 * 64 * 8) return;
    int j    = idx & 7;
    int lane = (idx >> 3) & 63;
    int ks   = (idx >> 9) & 3;
    int mt2  = (idx >> 11) & 7;
    int k    = idx >> 14;
    int o = mt2 * 16 + (lane & 15);
    int c = ks * 32 + (lane >> 4) * 8 + j;
    af[idx] = (__bf16)w[(o * CC + c) * 9 + k];
}

// ---------------------------------------------------------------------------
// Kernel 1: init off with bias (so conv partials can atomicAdd).
// ---------------------------------------------------------------------------
__global__ __launch_bounds__(256) void off_init_kernel(
    const float* __restrict__ ob, float* __restrict__ off)
{
    int idx = blockIdx.x * 256 + threadIdx.x;
    if (idx >= BB * NOFF * HH * WW) return;
    int oc = (idx >> 12) % NOFF;
    off[idx] = ob[oc];
}

// ---------------------------------------------------------------------------
// Kernel 2: offset conv, split over kh (blockIdx.z) for 3x occupancy.
// Block=(h,b,kh), 256 thr: lane=w, wave=ic quarter. LDS reduce + atomicAdd.
// ---------------------------------------------------------------------------
__global__ __launch_bounds__(256) void offset_conv_kh_kernel(
    const float* __restrict__ x, const float* __restrict__ u,
    const float* __restrict__ ow, float* __restrict__ off)
{
    const int h  = blockIdx.x;
    const int b  = blockIdx.y;
    const int kh = blockIdx.z;
    const int y  = h - 1 + kh;
    if (y < 0 || y >= HH) return;   // uniform per block

    const int lane = threadIdx.x & 63;
    const int wv   = threadIdx.x >> 6;

    float acc[NOFF];
#pragma unroll
    for (int i = 0; i < NOFF; ++i) acc[i] = 0.f;

    for (int icl = 0; icl < 64; ++icl) {
        int ic = wv * 64 + icl;
        const float* src = (ic < CC)
            ? (x + ((size_t)(b * CC + ic) * HH + y) * WW)
            : (u + ((size_t)(b * CC + (ic - CC)) * HH + y) * WW);
        float v0 = (lane >= 1)     ? src[lane - 1] : 0.f;
        float v1 = src[lane];
        float v2 = (lane < WW - 1) ? src[lane + 1] : 0.f;
        const float* wr = ow + (size_t)ic * 9 + kh * 3;
#pragma unroll
        for (int oc = 0; oc < NOFF; ++oc) {
            const float* wp = wr + (size_t)oc * (256 * 9);
            acc[oc] = fmaf(wp[0], v0, fmaf(wp[1], v1, fmaf(wp[2], v2, acc[oc])));
        }
    }

    __shared__ float part[4][NOFF][64];
#pragma unroll
    for (int oc = 0; oc < NOFF; ++oc) part[wv][oc][lane] = acc[oc];
    __syncthreads();

    for (int t = threadIdx.x; t < NOFF * 64; t += 256) {
        int oc = t >> 6;
        int w2 = t & 63;
        float s = part[0][oc][w2] + part[1][oc][w2] +
                  part[2][oc][w2] + part[3][oc][w2];
        atomicAdd(off + ((size_t)(b * NOFF + oc) * HH + h) * WW + w2, s);
    }
}

// ---------------------------------------------------------------------------
// Kernel 3: deformable sample (f32 gather -> bf16 LDS tile) + MFMA einsum.
// Block=(h,b). Phase A (once): bilinear weights/indices for all 9 taps, with
// x-corner select folded into (ax,ay,bx,by) so each row needs ONE float2 load.
// Phase B per tap: fill sampT[w][c] bf16 (c-contig, stride 136 for banks).
// Phase C per tap: 16x16x32 bf16 MFMA, wave wv -> oc [wv*32, wv*32+32).
// ---------------------------------------------------------------------------
__global__ __launch_bounds__(256) void fam_main_kernel(
    const float* __restrict__ u, const __bf16* __restrict__ af,
    const float* __restrict__ bias, const float* __restrict__ off,
    float* __restrict__ out)
{
    const int h    = blockIdx.x;
    const int b    = blockIdx.y;
    const int tid  = threadIdx.x;
    const int lane = tid & 63;
    const int wv   = tid >> 6;
    const int col  = lane & 15;
    const int quad = lane >> 4;

    __shared__ __align__(16) __bf16 sampT[64][136];   // [w][c], padded stride
    __shared__ float s_ax[9][64], s_ay[9][64], s_bx[9][64], s_by[9][64];
    __shared__ int   s_i0[9][64], s_i1[9][64];

    // ---- Phase A: all 9 taps' bilinear coeffs ----
    for (int t = tid; t < 9 * 64; t += 256) {
        int k  = t >> 6;
        int wq = t & 63;
        float dy = off[((size_t)(b * NOFF + 2 * k)     * HH + h) * WW + wq];
        float dx = off[((size_t)(b * NOFF + 2 * k + 1) * HH + h) * WW + wq];
        float py = (float)(h - 1 + k / 3) + dy;
        float px = (float)(wq - 1 + k % 3) + dx;
        float y0f = floorf(py), x0f = floorf(px);
        int y0 = (int)y0f, x0 = (int)x0f;
        float fy = py - y0f, fx = px - x0f;
        bool vy0 = (y0 >= 0) && (y0 < HH);
        bool vy1 = (y0 + 1 >= 0) && (y0 + 1 < HH);
        bool vx0 = (x0 >= 0) && (x0 < WW);
        bool vx1 = (x0 + 1 >= 0) && (x0 + 1 < WW);
        float w00 = (1.f - fy) * (1.f - fx) * ((vy0 && vx0) ? 1.f : 0.f);
        float w01 = (1.f - fy) * fx         * ((vy0 && vx1) ? 1.f : 0.f);
        float w10 = fy * (1.f - fx)         * ((vy1 && vx0) ? 1.f : 0.f);
        float w11 = fy * fx                 * ((vy1 && vx1) ? 1.f : 0.f);
        int y0c = min(max(y0, 0), HH - 1);
        int y1c = min(max(y0 + 1, 0), HH - 1);
        int x0c = min(max(x0, 0), WW - 1);
        int x1c = min(max(x0 + 1, 0), WW - 1);
        int xl  = min(max(x0, 0), WW - 2);
        // fold corner-select into weights: value = ax*row[xl] + ay*row[xl+1]
        float ax = ((x0c == xl)     ? w00 : 0.f) + ((x1c == xl)     ? w01 : 0.f);
        float ay = ((x0c == xl + 1) ? w00 : 0.f) + ((x1c == xl + 1) ? w01 : 0.f);
        float bx = ((x0c == xl)     ? w10 : 0.f) + ((x1c == xl)     ? w11 : 0.f);
        float by = ((x0c == xl + 1) ? w10 : 0.f) + ((x1c == xl + 1) ? w11 : 0.f);
        s_ax[k][wq] = ax; s_ay[k][wq] = ay;
        s_bx[k][wq] = bx; s_by[k][wq] = by;
        s_i0[k][wq] = y0c * WW + xl;
        s_i1[k][wq] = y1c * WW + xl;
    }
    __syncthreads();

    f32x4 acc[2][4];
#pragma unroll
    for (int mt = 0; mt < 2; ++mt)
#pragma unroll
        for (int nt = 0; nt < 4; ++nt) acc[mt][nt] = (f32x4){0.f, 0.f, 0.f, 0.f};

    const float* ub = u + (size_t)b * (CC * HH * WW);
    const bf16x8* afp = (const bf16x8*)af;

    for (int k = 0; k < 9; ++k) {
        // ---- Phase B: gather + pack bf16 into sampT ----
        {
            float ax = s_ax[k][lane], ay = s_ay[k][lane];
            float bx = s_bx[k][lane], by = s_by[k][lane];
            int   i0 = s_i0[k][lane], i1 = s_i1[k][lane];
#pragma unroll
            for (int g = 0; g < 4; ++g) {
                bf16x8 pk;
#pragma unroll
                for (int j = 0; j < 8; ++j) {
                    const float* up = ub + (size_t)(wv * 32 + g * 8 + j) * (HH * WW);
                    f32x2u r0 = *(const f32x2u*)(up + i0);
                    f32x2u r1 = *(const f32x2u*)(up + i1);
                    float v = ax * r0.x + ay * r0.y + bx * r1.x + by * r1.y;
                    pk[j] = (__bf16)v;
                }
                *(bf16x8*)&sampT[lane][wv * 32 + g * 8] = pk;
            }
        }
        __syncthreads();

        // ---- Phase C: MFMA.  A = weights (o x c), B = sampT (c x w) ----
#pragma unroll
        for (int ks = 0; ks < 4; ++ks) {
            bf16x8 a0 = afp[((k * 8 + wv * 2 + 0) * 4 + ks) * 64 + lane];
            bf16x8 a1 = afp[((k * 8 + wv * 2 + 1) * 4 + ks) * 64 + lane];
            int crow = ks * 32 + quad * 8;
#pragma unroll
            for (int nt = 0; nt < 4; ++nt) {
                bf16x8 bfrag = *(const bf16x8*)&sampT[nt * 16 + col][crow];
                acc[0][nt] = __builtin_amdgcn_mfma_f32_16x16x32_bf16(
                    a0, bfrag, acc[0][nt], 0, 0, 0);
                acc[1][nt] = __builtin_amdgcn_mfma_f32_16x16x32_bf16(
                    a1, bfrag, acc[1][nt], 0, 0, 0);
            }
        }
        __syncthreads();
    }

    // ---- Epilogue: D layout col=lane&15, row=quad*4+reg ----
#pragma unroll
    for (int mt = 0; mt < 2; ++mt) {
#pragma unroll
        for (int r = 0; r < 4; ++r) {
            int o = wv * 32 + mt * 16 + quad * 4 + r;
            float bv = bias[o];
#pragma unroll
            for (int nt = 0; nt < 4; ++nt)
                out[((size_t)(b * CC + o) * HH + h) * WW + nt * 16 + col] =
                    acc[mt][nt][r] + bv;
        }
    }
}

extern "C" void kernel_launch(void* const* d_in, const int* in_sizes, int n_in,
                              void* d_out, int out_size, void* d_ws, size_t ws_size,
                              hipStream_t stream) {
    const float* x    = (const float*)d_in[0];
    const float* u    = (const float*)d_in[1];
    const float* wgt  = (const float*)d_in[2];
    const float* bias = (const float*)d_in[3];
    const float* ow   = (const float*)d_in[4];
    const float* ob   = (const float*)d_in[5];
    float* out = (float*)d_out;

    float*  off = (float*)d_ws;                                  // 1,179,648 B
    __bf16* af  = (__bf16*)((char*)d_ws + (size_t)BB * NOFF * HH * WW * 4);

    hipLaunchKernelGGL(prep_afrag_kernel, dim3(576), dim3(256), 0, stream, wgt, af);
    hipLaunchKernelGGL(off_init_kernel, dim3(2304), dim3(256), 0, stream, ob, off);
    hipLaunchKernelGGL(offset_conv_kh_kernel, dim3(HH, BB, 3), dim3(256), 0, stream,
                       x, u, ow, off);
    hipLaunchKernelGGL(fam_main_kernel, dim3(HH, BB), dim3(256), 0, stream,
                       u, af, bias, off, out);
}

// Round 5
// 190.603 us; speedup vs baseline: 2.7323x; 1.9949x over previous
//
#include <hip/hip_runtime.h>

#define BB 8
#define CC 128
#define HH 64
#define WW 64
#define NOFF 18

typedef __bf16 bf16x8 __attribute__((ext_vector_type(8)));
typedef float  f32x4  __attribute__((ext_vector_type(4)));
typedef float  f32x2u __attribute__((ext_vector_type(2), aligned(4)));

// ---------------------------------------------------------------------------
// Kernel 0: pack both weight tensors into bf16 MFMA A-fragments.
//  af  (main einsum): idx=(((k*8+mt2)*4+ks)*64+lane)*8+j,
//      A[o=mt2*16+(lane&15)][c=ks*32+(lane>>4)*8+j] of w[o][c][k]      (147456 el)
//  waf (offset conv): t=(((kk*2+mt)*8+ks)*64+lane)*8+j,
//      A[oc=mt*16+(lane&15)][ic=ks*32+(lane>>4)*8+j] of ow[oc][ic][kk],
//      zero-padded for oc>=18.                                          (73728 el)
// ---------------------------------------------------------------------------
__global__ __launch_bounds__(256) void prep_kernel(
    const float* __restrict__ w, const float* __restrict__ ow,
    __bf16* __restrict__ af, __bf16* __restrict__ waf)
{
    int idx = blockIdx.x * 256 + threadIdx.x;
    if (idx < 147456) {
        int j    = idx & 7;
        int lane = (idx >> 3) & 63;
        int ks   = (idx >> 9) & 3;
        int mt2  = (idx >> 11) & 7;
        int k    = idx >> 14;
        int o = mt2 * 16 + (lane & 15);
        int c = ks * 32 + (lane >> 4) * 8 + j;
        af[idx] = (__bf16)w[(o * CC + c) * 9 + k];
    } else if (idx < 147456 + 73728) {
        int t    = idx - 147456;
        int j    = t & 7;
        int lane = (t >> 3) & 63;
        int ks   = (t >> 9) & 7;
        int mt   = (t >> 12) & 1;
        int kk   = t >> 13;
        int oc = mt * 16 + (lane & 15);
        int ic = ks * 32 + (lane >> 4) * 8 + j;
        float v = (oc < NOFF) ? ow[(oc * 256 + ic) * 9 + kk] : 0.f;
        waf[t] = (__bf16)v;
    }
}

// ---------------------------------------------------------------------------
// Kernel 1: offset conv as MFMA implicit GEMM.
// Block = (b,h) with b = id&7 (XCD locality). M=32(18 oc), N=64 px, K=2304.
// Per kh: stage concat row y into bf16 LDS tile T[w+1][ic] (rows 0,65 = zero
// padding); per kw: B-frag = T[n+kw][ks*32+quad*8..], A-frag prepacked.
// TS=264: row stride 528 B = 33*16 -> every ds_read_b128 16-B aligned.
// ---------------------------------------------------------------------------
#define TS 264
__global__ __launch_bounds__(256) void offset_conv_mfma_kernel(
    const float* __restrict__ x, const float* __restrict__ u,
    const __bf16* __restrict__ waf, const float* __restrict__ ob,
    float* __restrict__ off)
{
    const int id   = blockIdx.x;
    const int b    = id & 7;
    const int h    = id >> 3;
    const int tid  = threadIdx.x;
    const int lane = tid & 63;
    const int wv   = tid >> 6;
    const int col  = lane & 15;
    const int quad = lane >> 4;

    __shared__ __align__(16) __bf16 T[66][TS];

    // zero the padding rows (conv zero-padding in w)
    {
        int ic = tid;                 // 0..255
        T[0][ic]  = (__bf16)0.f;
        T[65][ic] = (__bf16)0.f;
    }

    f32x4 acc0 = {0.f, 0.f, 0.f, 0.f};
    f32x4 acc1 = {0.f, 0.f, 0.f, 0.f};

    const bf16x8* wafp = (const bf16x8*)waf;

    for (int kh = 0; kh < 3; ++kh) {
        int y = h - 1 + kh;
        if (y < 0 || y >= HH) continue;          // block-uniform
        __syncthreads();                          // protect prev tile reads
        // stage concat[b, :, y, :] -> T[w+1][ic]  (bf16, b128 writes)
        {
            int w2 = lane;
#pragma unroll
            for (int g = 0; g < 8; ++g) {
                bf16x8 pk;
#pragma unroll
                for (int j = 0; j < 8; ++j) {
                    int ic = wv * 64 + g * 8 + j;
                    float v = (ic < CC)
                        ? x[((size_t)(b * CC + ic) * HH + y) * WW + w2]
                        : u[((size_t)(b * CC + (ic - CC)) * HH + y) * WW + w2];
                    pk[j] = (__bf16)v;
                }
                *(bf16x8*)&T[w2 + 1][wv * 64 + g * 8] = pk;
            }
        }
        __syncthreads();

        // wave wv owns pixels n = wv*16 .. wv*16+15
#pragma unroll
        for (int kw = 0; kw < 3; ++kw) {
            int kk = kh * 3 + kw;
            const __bf16* brow = &T[wv * 16 + col + kw][quad * 8];
#pragma unroll
            for (int ks = 0; ks < 8; ++ks) {
                bf16x8 bfrag = *(const bf16x8*)(brow + ks * 32);
                bf16x8 a0 = wafp[((kk * 2 + 0) * 8 + ks) * 64 + lane];
                bf16x8 a1 = wafp[((kk * 2 + 1) * 8 + ks) * 64 + lane];
                acc0 = __builtin_amdgcn_mfma_f32_16x16x32_bf16(a0, bfrag, acc0, 0, 0, 0);
                acc1 = __builtin_amdgcn_mfma_f32_16x16x32_bf16(a1, bfrag, acc1, 0, 0, 0);
            }
        }
    }

    // epilogue: D col=lane&15 -> pixel, row=quad*4+r -> oc
    int w2 = wv * 16 + col;
#pragma unroll
    for (int r = 0; r < 4; ++r) {
        int oc = quad * 4 + r;
        off[((size_t)(b * NOFF + oc) * HH + h) * WW + w2] = acc0[r] + ob[oc];
    }
#pragma unroll
    for (int r = 0; r < 4; ++r) {
        int oc = 16 + quad * 4 + r;
        if (oc < NOFF)
            off[((size_t)(b * NOFF + oc) * HH + h) * WW + w2] = acc1[r] + ob[oc];
    }
}

// ---------------------------------------------------------------------------
// Kernel 2: deformable sample (f32 gather -> bf16 LDS tile) + MFMA einsum.
// Block = (b,h), b = id&7 for XCD/L2 locality on u[b] (2 MB per batch).
// ---------------------------------------------------------------------------
__global__ __launch_bounds__(256) void fam_main_kernel(
    const float* __restrict__ u, const __bf16* __restrict__ af,
    const float* __restrict__ bias, const float* __restrict__ off,
    float* __restrict__ out)
{
    const int id   = blockIdx.x;
    const int b    = id & 7;
    const int h    = id >> 3;
    const int tid  = threadIdx.x;
    const int lane = tid & 63;
    const int wv   = tid >> 6;
    const int col  = lane & 15;
    const int quad = lane >> 4;

    __shared__ __align__(16) __bf16 sampT[64][136];   // [w][c], 272 B rows
    __shared__ float s_ax[9][64], s_ay[9][64], s_bx[9][64], s_by[9][64];
    __shared__ int   s_i0[9][64], s_i1[9][64];

    // ---- Phase A: bilinear coeffs for all 9 taps ----
    for (int t = tid; t < 9 * 64; t += 256) {
        int k  = t >> 6;
        int wq = t & 63;
        float dy = off[((size_t)(b * NOFF + 2 * k)     * HH + h) * WW + wq];
        float dx = off[((size_t)(b * NOFF + 2 * k + 1) * HH + h) * WW + wq];
        float py = (float)(h - 1 + k / 3) + dy;
        float px = (float)(wq - 1 + k % 3) + dx;
        float y0f = floorf(py), x0f = floorf(px);
        int y0 = (int)y0f, x0 = (int)x0f;
        float fy = py - y0f, fx = px - x0f;
        bool vy0 = (y0 >= 0) && (y0 < HH);
        bool vy1 = (y0 + 1 >= 0) && (y0 + 1 < HH);
        bool vx0 = (x0 >= 0) && (x0 < WW);
        bool vx1 = (x0 + 1 >= 0) && (x0 + 1 < WW);
        float w00 = (1.f - fy) * (1.f - fx) * ((vy0 && vx0) ? 1.f : 0.f);
        float w01 = (1.f - fy) * fx         * ((vy0 && vx1) ? 1.f : 0.f);
        float w10 = fy * (1.f - fx)         * ((vy1 && vx0) ? 1.f : 0.f);
        float w11 = fy * fx                 * ((vy1 && vx1) ? 1.f : 0.f);
        int y0c = min(max(y0, 0), HH - 1);
        int y1c = min(max(y0 + 1, 0), HH - 1);
        int x0c = min(max(x0, 0), WW - 1);
        int x1c = min(max(x0 + 1, 0), WW - 1);
        int xl  = min(max(x0, 0), WW - 2);
        float ax = ((x0c == xl)     ? w00 : 0.f) + ((x1c == xl)     ? w01 : 0.f);
        float ay = ((x0c == xl + 1) ? w00 : 0.f) + ((x1c == xl + 1) ? w01 : 0.f);
        float bx = ((x0c == xl)     ? w10 : 0.f) + ((x1c == xl)     ? w11 : 0.f);
        float by = ((x0c == xl + 1) ? w10 : 0.f) + ((x1c == xl + 1) ? w11 : 0.f);
        s_ax[k][wq] = ax; s_ay[k][wq] = ay;
        s_bx[k][wq] = bx; s_by[k][wq] = by;
        s_i0[k][wq] = y0c * WW + xl;
        s_i1[k][wq] = y1c * WW + xl;
    }
    __syncthreads();

    f32x4 acc[2][4];
#pragma unroll
    for (int mt = 0; mt < 2; ++mt)
#pragma unroll
        for (int nt = 0; nt < 4; ++nt) acc[mt][nt] = (f32x4){0.f, 0.f, 0.f, 0.f};

    const float* ub = u + (size_t)b * (CC * HH * WW);
    const bf16x8* afp = (const bf16x8*)af;

    for (int k = 0; k < 9; ++k) {
        // ---- Phase B: gather + pack bf16 into sampT ----
        {
            float ax = s_ax[k][lane], ay = s_ay[k][lane];
            float bx = s_bx[k][lane], by = s_by[k][lane];
            int   i0 = s_i0[k][lane], i1 = s_i1[k][lane];
#pragma unroll 4
            for (int g = 0; g < 4; ++g) {
                bf16x8 pk;
#pragma unroll
                for (int j = 0; j < 8; ++j) {
                    const float* up = ub + (size_t)(wv * 32 + g * 8 + j) * (HH * WW);
                    f32x2u r0 = *(const f32x2u*)(up + i0);
                    f32x2u r1 = *(const f32x2u*)(up + i1);
                    float v = ax * r0.x + ay * r0.y + bx * r1.x + by * r1.y;
                    pk[j] = (__bf16)v;
                }
                *(bf16x8*)&sampT[lane][wv * 32 + g * 8] = pk;
            }
        }
        __syncthreads();

        // ---- Phase C: MFMA ----
#pragma unroll
        for (int ks = 0; ks < 4; ++ks) {
            bf16x8 a0 = afp[((k * 8 + wv * 2 + 0) * 4 + ks) * 64 + lane];
            bf16x8 a1 = afp[((k * 8 + wv * 2 + 1) * 4 + ks) * 64 + lane];
            int crow = ks * 32 + quad * 8;
#pragma unroll
            for (int nt = 0; nt < 4; ++nt) {
                bf16x8 bfrag = *(const bf16x8*)&sampT[nt * 16 + col][crow];
                acc[0][nt] = __builtin_amdgcn_mfma_f32_16x16x32_bf16(
                    a0, bfrag, acc[0][nt], 0, 0, 0);
                acc[1][nt] = __builtin_amdgcn_mfma_f32_16x16x32_bf16(
                    a1, bfrag, acc[1][nt], 0, 0, 0);
            }
        }
        __syncthreads();
    }

    // ---- Epilogue ----
#pragma unroll
    for (int mt = 0; mt < 2; ++mt) {
#pragma unroll
        for (int r = 0; r < 4; ++r) {
            int o = wv * 32 + mt * 16 + quad * 4 + r;
            float bv = bias[o];
#pragma unroll
            for (int nt = 0; nt < 4; ++nt)
                out[((size_t)(b * CC + o) * HH + h) * WW + nt * 16 + col] =
                    acc[mt][nt][r] + bv;
        }
    }
}

extern "C" void kernel_launch(void* const* d_in, const int* in_sizes, int n_in,
                              void* d_out, int out_size, void* d_ws, size_t ws_size,
                              hipStream_t stream) {
    const float* x    = (const float*)d_in[0];
    const float* u    = (const float*)d_in[1];
    const float* wgt  = (const float*)d_in[2];
    const float* bias = (const float*)d_in[3];
    const float* ow   = (const float*)d_in[4];
    const float* ob   = (const float*)d_in[5];
    float* out = (float*)d_out;

    // Workspace layout — ELEMENT-typed pointer arithmetic only.
    // off: 8*18*64*64 f32 = 2,359,296 B; af: 147456 bf16; waf: 73728 bf16.
    // (R3/R4 bug: af placed at a wrong BYTE literal halfway inside off ->
    //  conv clobbered weights while other blocks read them -> NaN.)
    float*  off = (float*)d_ws;
    __bf16* af  = (__bf16*)(off + (size_t)BB * NOFF * HH * WW);
    __bf16* waf = af + 147456;

    hipLaunchKernelGGL(prep_kernel, dim3(864), dim3(256), 0, stream,
                       wgt, ow, af, waf);
    hipLaunchKernelGGL(offset_conv_mfma_kernel, dim3(512), dim3(256), 0, stream,
                       x, u, waf, ob, off);
    hipLaunchKernelGGL(fam_main_kernel, dim3(512), dim3(256), 0, stream,
                       u, af, bias, off, out);
}

// Round 6
// 137.313 us; speedup vs baseline: 3.7927x; 1.3881x over previous
//
#include <hip/hip_runtime.h>

#define BB 8
#define CC 128
#define HH 64
#define WW 64
#define NOFF 18

typedef __bf16 bf16x8 __attribute__((ext_vector_type(8)));
typedef float  f32x4  __attribute__((ext_vector_type(4)));
typedef float  f32x2u __attribute__((ext_vector_type(2), aligned(4)));

// ---------------------------------------------------------------------------
// Kernel 0: pack both weight tensors into bf16 MFMA A-fragments.
// ---------------------------------------------------------------------------
__global__ __launch_bounds__(256) void prep_kernel(
    const float* __restrict__ w, const float* __restrict__ ow,
    __bf16* __restrict__ af, __bf16* __restrict__ waf)
{
    int idx = blockIdx.x * 256 + threadIdx.x;
    if (idx < 147456) {
        int j    = idx & 7;
        int lane = (idx >> 3) & 63;
        int ks   = (idx >> 9) & 3;
        int mt2  = (idx >> 11) & 7;
        int k    = idx >> 14;
        int o = mt2 * 16 + (lane & 15);
        int c = ks * 32 + (lane >> 4) * 8 + j;
        af[idx] = (__bf16)w[(o * CC + c) * 9 + k];
    } else if (idx < 147456 + 73728) {
        int t    = idx - 147456;
        int j    = t & 7;
        int lane = (t >> 3) & 63;
        int ks   = (t >> 9) & 7;
        int mt   = (t >> 12) & 1;
        int kk   = t >> 13;
        int oc = mt * 16 + (lane & 15);
        int ic = ks * 32 + (lane >> 4) * 8 + j;
        float v = (oc < NOFF) ? ow[(oc * 256 + ic) * 9 + kk] : 0.f;
        waf[t] = (__bf16)v;
    }
}

// ---------------------------------------------------------------------------
// Kernel T: NCHW f32 (x ‖ u) -> NHWC bf16 ct[b][y][w][ic0..255].
// Block=(b,y). Stage via LDS, write coalesced b128.
// ---------------------------------------------------------------------------
__global__ __launch_bounds__(256) void transpose_kernel(
    const float* __restrict__ x, const float* __restrict__ u,
    __bf16* __restrict__ ct)
{
    const int id   = blockIdx.x;
    const int b    = id & 7;
    const int y    = id >> 3;
    const int tid  = threadIdx.x;
    const int lane = tid & 63;
    const int wv   = tid >> 6;

    __shared__ __align__(16) __bf16 t[64][264];   // 528-B rows (33*16)

#pragma unroll
    for (int g = 0; g < 8; ++g) {
        bf16x8 pk;
#pragma unroll
        for (int j = 0; j < 8; ++j) {
            int ic = wv * 64 + g * 8 + j;
            float v = (ic < CC)
                ? x[((size_t)(b * CC + ic) * HH + y) * WW + lane]
                : u[((size_t)(b * CC + (ic - CC)) * HH + y) * WW + lane];
            pk[j] = (__bf16)v;
        }
        *(bf16x8*)&t[lane][wv * 64 + g * 8] = pk;
    }
    __syncthreads();

    __bf16* dst = ct + (size_t)(b * HH + y) * WW * 256;
#pragma unroll
    for (int p = 0; p < 8; ++p) {
        int idx = p * 256 + tid;
        int px = idx >> 5, ch = idx & 31;
        *(bf16x8*)(dst + px * 256 + ch * 8) = *(const bf16x8*)&t[px][ch * 8];
    }
}

// ---------------------------------------------------------------------------
// Kernel 1 (fast): offset conv MFMA, staging from ct (coalesced 1-KB instrs).
// ---------------------------------------------------------------------------
#define TS 264
__global__ __launch_bounds__(256) void offset_conv_fast_kernel(
    const __bf16* __restrict__ ct, const __bf16* __restrict__ waf,
    const float* __restrict__ ob, float* __restrict__ off)
{
    const int id   = blockIdx.x;
    const int b    = id & 7;
    const int h    = id >> 3;
    const int tid  = threadIdx.x;
    const int lane = tid & 63;
    const int wv   = tid >> 6;
    const int col  = lane & 15;
    const int quad = lane >> 4;

    __shared__ __align__(16) __bf16 T[66][TS];
    {
        int ic = tid;
        T[0][ic]  = (__bf16)0.f;
        T[65][ic] = (__bf16)0.f;
    }

    f32x4 acc0 = {0.f, 0.f, 0.f, 0.f};
    f32x4 acc1 = {0.f, 0.f, 0.f, 0.f};
    const bf16x8* wafp = (const bf16x8*)waf;

    for (int kh = 0; kh < 3; ++kh) {
        int y = h - 1 + kh;
        if (y < 0 || y >= HH) continue;          // block-uniform
        __syncthreads();
        const __bf16* row = ct + (size_t)(b * HH + y) * WW * 256;
#pragma unroll
        for (int p = 0; p < 8; ++p) {
            int idx = p * 256 + tid;
            int px = idx >> 5, ch = idx & 31;
            *(bf16x8*)&T[px + 1][ch * 8] = *(const bf16x8*)(row + px * 256 + ch * 8);
        }
        __syncthreads();

#pragma unroll
        for (int kw = 0; kw < 3; ++kw) {
            int kk = kh * 3 + kw;
            const __bf16* brow = &T[wv * 16 + col + kw][quad * 8];
#pragma unroll
            for (int ks = 0; ks < 8; ++ks) {
                bf16x8 bfrag = *(const bf16x8*)(brow + ks * 32);
                bf16x8 a0 = wafp[((kk * 2 + 0) * 8 + ks) * 64 + lane];
                bf16x8 a1 = wafp[((kk * 2 + 1) * 8 + ks) * 64 + lane];
                acc0 = __builtin_amdgcn_mfma_f32_16x16x32_bf16(a0, bfrag, acc0, 0, 0, 0);
                acc1 = __builtin_amdgcn_mfma_f32_16x16x32_bf16(a1, bfrag, acc1, 0, 0, 0);
            }
        }
    }

    int w2 = wv * 16 + col;
#pragma unroll
    for (int r = 0; r < 4; ++r) {
        int oc = quad * 4 + r;
        off[((size_t)(b * NOFF + oc) * HH + h) * WW + w2] = acc0[r] + ob[oc];
    }
#pragma unroll
    for (int r = 0; r < 4; ++r) {
        int oc = 16 + quad * 4 + r;
        if (oc < NOFF)
            off[((size_t)(b * NOFF + oc) * HH + h) * WW + w2] = acc1[r] + ob[oc];
    }
}

// ---------------------------------------------------------------------------
// Kernel 2 (fast): deformable sample from ct (coalesced corner rows) + MFMA.
// ---------------------------------------------------------------------------
__global__ __launch_bounds__(256) void fam_main_fast_kernel(
    const __bf16* __restrict__ ct, const __bf16* __restrict__ af,
    const float* __restrict__ bias, const float* __restrict__ off,
    float* __restrict__ out)
{
    const int id   = blockIdx.x;
    const int b    = id & 7;
    const int h    = id >> 3;
    const int tid  = threadIdx.x;
    const int lane = tid & 63;
    const int wv   = tid >> 6;
    const int col  = lane & 15;
    const int quad = lane >> 4;

    __shared__ __align__(16) __bf16 sampT[64][136];
    __shared__ float s_ax[9][64], s_ay[9][64], s_bx[9][64], s_by[9][64];
    __shared__ int   s_i0[9][64], s_i1[9][64];

    // ---- Phase A: bilinear coeffs for all 9 taps ----
    for (int t = tid; t < 9 * 64; t += 256) {
        int k  = t >> 6;
        int wq = t & 63;
        float dy = off[((size_t)(b * NOFF + 2 * k)     * HH + h) * WW + wq];
        float dx = off[((size_t)(b * NOFF + 2 * k + 1) * HH + h) * WW + wq];
        float py = (float)(h - 1 + k / 3) + dy;
        float px = (float)(wq - 1 + k % 3) + dx;
        float y0f = floorf(py), x0f = floorf(px);
        int y0 = (int)y0f, x0 = (int)x0f;
        float fy = py - y0f, fx = px - x0f;
        bool vy0 = (y0 >= 0) && (y0 < HH);
        bool vy1 = (y0 + 1 >= 0) && (y0 + 1 < HH);
        bool vx0 = (x0 >= 0) && (x0 < WW);
        bool vx1 = (x0 + 1 >= 0) && (x0 + 1 < WW);
        float w00 = (1.f - fy) * (1.f - fx) * ((vy0 && vx0) ? 1.f : 0.f);
        float w01 = (1.f - fy) * fx         * ((vy0 && vx1) ? 1.f : 0.f);
        float w10 = fy * (1.f - fx)         * ((vy1 && vx0) ? 1.f : 0.f);
        float w11 = fy * fx                 * ((vy1 && vx1) ? 1.f : 0.f);
        int y0c = min(max(y0, 0), HH - 1);
        int y1c = min(max(y0 + 1, 0), HH - 1);
        int x0c = min(max(x0, 0), WW - 1);
        int x1c = min(max(x0 + 1, 0), WW - 1);
        int xl  = min(max(x0, 0), WW - 2);
        float ax = ((x0c == xl)     ? w00 : 0.f) + ((x1c == xl)     ? w01 : 0.f);
        float ay = ((x0c == xl + 1) ? w00 : 0.f) + ((x1c == xl + 1) ? w01 : 0.f);
        float bx = ((x0c == xl)     ? w10 : 0.f) + ((x1c == xl)     ? w11 : 0.f);
        float by = ((x0c == xl + 1) ? w10 : 0.f) + ((x1c == xl + 1) ? w11 : 0.f);
        s_ax[k][wq] = ax; s_ay[k][wq] = ay;
        s_bx[k][wq] = bx; s_by[k][wq] = by;
        s_i0[k][wq] = y0c * WW + xl;     // pixel-record index into ct[b]
        s_i1[k][wq] = y1c * WW + xl;
    }
    __syncthreads();

    f32x4 acc[2][4];
#pragma unroll
    for (int mt = 0; mt < 2; ++mt)
#pragma unroll
        for (int nt = 0; nt < 4; ++nt) acc[mt][nt] = (f32x4){0.f, 0.f, 0.f, 0.f};

    const __bf16* ctb = ct + (size_t)b * (HH * WW * 256);
    const bf16x8* afp = (const bf16x8*)af;

    for (int k = 0; k < 9; ++k) {
        // ---- Phase B: coalesced corner-row gather, weighted sum, pack ----
#pragma unroll
        for (int p = 0; p < 4; ++p) {
            int idx = p * 256 + tid;
            int px = idx >> 4, ch = idx & 15;
            float ax = s_ax[k][px], ay = s_ay[k][px];
            float bx = s_bx[k][px], by = s_by[k][px];
            const __bf16* r0 = ctb + (size_t)s_i0[k][px] * 256 + 128 + ch * 8;
            const __bf16* r1 = ctb + (size_t)s_i1[k][px] * 256 + 128 + ch * 8;
            bf16x8 A  = *(const bf16x8*)r0;
            bf16x8 Bv = *(const bf16x8*)(r0 + 256);
            bf16x8 Cv = *(const bf16x8*)r1;
            bf16x8 Dv = *(const bf16x8*)(r1 + 256);
            bf16x8 res;
#pragma unroll
            for (int j = 0; j < 8; ++j)
                res[j] = (__bf16)(ax * (float)A[j] + ay * (float)Bv[j] +
                                  bx * (float)Cv[j] + by * (float)Dv[j]);
            *(bf16x8*)&sampT[px][ch * 8] = res;
        }
        __syncthreads();

        // ---- Phase C: MFMA ----
#pragma unroll
        for (int ks = 0; ks < 4; ++ks) {
            bf16x8 a0 = afp[((k * 8 + wv * 2 + 0) * 4 + ks) * 64 + lane];
            bf16x8 a1 = afp[((k * 8 + wv * 2 + 1) * 4 + ks) * 64 + lane];
            int crow = ks * 32 + quad * 8;
#pragma unroll
            for (int nt = 0; nt < 4; ++nt) {
                bf16x8 bfrag = *(const bf16x8*)&sampT[nt * 16 + col][crow];
                acc[0][nt] = __builtin_amdgcn_mfma_f32_16x16x32_bf16(
                    a0, bfrag, acc[0][nt], 0, 0, 0);
                acc[1][nt] = __builtin_amdgcn_mfma_f32_16x16x32_bf16(
                    a1, bfrag, acc[1][nt], 0, 0, 0);
            }
        }
        __syncthreads();
    }

#pragma unroll
    for (int mt = 0; mt < 2; ++mt) {
#pragma unroll
        for (int r = 0; r < 4; ++r) {
            int o = wv * 32 + mt * 16 + quad * 4 + r;
            float bv = bias[o];
#pragma unroll
            for (int nt = 0; nt < 4; ++nt)
                out[((size_t)(b * CC + o) * HH + h) * WW + nt * 16 + col] =
                    acc[mt][nt][r] + bv;
        }
    }
}

// ===========================================================================
// Fallback path (R5, needs only 2.8 MB ws) — used if ws_size is too small.
// ===========================================================================
__global__ __launch_bounds__(256) void offset_conv_mfma_kernel(
    const float* __restrict__ x, const float* __restrict__ u,
    const __bf16* __restrict__ waf, const float* __restrict__ ob,
    float* __restrict__ off)
{
    const int id   = blockIdx.x;
    const int b    = id & 7;
    const int h    = id >> 3;
    const int tid  = threadIdx.x;
    const int lane = tid & 63;
    const int wv   = tid >> 6;
    const int col  = lane & 15;
    const int quad = lane >> 4;

    __shared__ __align__(16) __bf16 T[66][TS];
    {
        int ic = tid;
        T[0][ic]  = (__bf16)0.f;
        T[65][ic] = (__bf16)0.f;
    }

    f32x4 acc0 = {0.f, 0.f, 0.f, 0.f};
    f32x4 acc1 = {0.f, 0.f, 0.f, 0.f};
    const bf16x8* wafp = (const bf16x8*)waf;

    for (int kh = 0; kh < 3; ++kh) {
        int y = h - 1 + kh;
        if (y < 0 || y >= HH) continue;
        __syncthreads();
        {
            int w2 = lane;
#pragma unroll
            for (int g = 0; g < 8; ++g) {
                bf16x8 pk;
#pragma unroll
                for (int j = 0; j < 8; ++j) {
                    int ic = wv * 64 + g * 8 + j;
                    float v = (ic < CC)
                        ? x[((size_t)(b * CC + ic) * HH + y) * WW + w2]
                        : u[((size_t)(b * CC + (ic - CC)) * HH + y) * WW + w2];
                    pk[j] = (__bf16)v;
                }
                *(bf16x8*)&T[w2 + 1][wv * 64 + g * 8] = pk;
            }
        }
        __syncthreads();

#pragma unroll
        for (int kw = 0; kw < 3; ++kw) {
            int kk = kh * 3 + kw;
            const __bf16* brow = &T[wv * 16 + col + kw][quad * 8];
#pragma unroll
            for (int ks = 0; ks < 8; ++ks) {
                bf16x8 bfrag = *(const bf16x8*)(brow + ks * 32);
                bf16x8 a0 = wafp[((kk * 2 + 0) * 8 + ks) * 64 + lane];
                bf16x8 a1 = wafp[((kk * 2 + 1) * 8 + ks) * 64 + lane];
                acc0 = __builtin_amdgcn_mfma_f32_16x16x32_bf16(a0, bfrag, acc0, 0, 0, 0);
                acc1 = __builtin_amdgcn_mfma_f32_16x16x32_bf16(a1, bfrag, acc1, 0, 0, 0);
            }
        }
    }

    int w2 = wv * 16 + col;
#pragma unroll
    for (int r = 0; r < 4; ++r) {
        int oc = quad * 4 + r;
        off[((size_t)(b * NOFF + oc) * HH + h) * WW + w2] = acc0[r] + ob[oc];
    }
#pragma unroll
    for (int r = 0; r < 4; ++r) {
        int oc = 16 + quad * 4 + r;
        if (oc < NOFF)
            off[((size_t)(b * NOFF + oc) * HH + h) * WW + w2] = acc1[r] + ob[oc];
    }
}

__global__ __launch_bounds__(256) void fam_main_kernel(
    const float* __restrict__ u, const __bf16* __restrict__ af,
    const float* __restrict__ bias, const float* __restrict__ off,
    float* __restrict__ out)
{
    const int id   = blockIdx.x;
    const int b    = id & 7;
    const int h    = id >> 3;
    const int tid  = threadIdx.x;
    const int lane = tid & 63;
    const int wv   = tid >> 6;
    const int col  = lane & 15;
    const int quad = lane >> 4;

    __shared__ __align__(16) __bf16 sampT[64][136];
    __shared__ float s_ax[9][64], s_ay[9][64], s_bx[9][64], s_by[9][64];
    __shared__ int   s_i0[9][64], s_i1[9][64];

    for (int t = tid; t < 9 * 64; t += 256) {
        int k  = t >> 6;
        int wq = t & 63;
        float dy = off[((size_t)(b * NOFF + 2 * k)     * HH + h) * WW + wq];
        float dx = off[((size_t)(b * NOFF + 2 * k + 1) * HH + h) * WW + wq];
        float py = (float)(h - 1 + k / 3) + dy;
        float px = (float)(wq - 1 + k % 3) + dx;
        float y0f = floorf(py), x0f = floorf(px);
        int y0 = (int)y0f, x0 = (int)x0f;
        float fy = py - y0f, fx = px - x0f;
        bool vy0 = (y0 >= 0) && (y0 < HH);
        bool vy1 = (y0 + 1 >= 0) && (y0 + 1 < HH);
        bool vx0 = (x0 >= 0) && (x0 < WW);
        bool vx1 = (x0 + 1 >= 0) && (x0 + 1 < WW);
        float w00 = (1.f - fy) * (1.f - fx) * ((vy0 && vx0) ? 1.f : 0.f);
        float w01 = (1.f - fy) * fx         * ((vy0 && vx1) ? 1.f : 0.f);
        float w10 = fy * (1.f - fx)         * ((vy1 && vx0) ? 1.f : 0.f);
        float w11 = fy * fx                 * ((vy1 && vx1) ? 1.f : 0.f);
        int y0c = min(max(y0, 0), HH - 1);
        int y1c = min(max(y0 + 1, 0), HH - 1);
        int x0c = min(max(x0, 0), WW - 1);
        int x1c = min(max(x0 + 1, 0), WW - 1);
        int xl  = min(max(x0, 0), WW - 2);
        float ax = ((x0c == xl)     ? w00 : 0.f) + ((x1c == xl)     ? w01 : 0.f);
        float ay = ((x0c == xl + 1) ? w00 : 0.f) + ((x1c == xl + 1) ? w01 : 0.f);
        float bx = ((x0c == xl)     ? w10 : 0.f) + ((x1c == xl)     ? w11 : 0.f);
        float by = ((x0c == xl + 1) ? w10 : 0.f) + ((x1c == xl + 1) ? w11 : 0.f);
        s_ax[k][wq] = ax; s_ay[k][wq] = ay;
        s_bx[k][wq] = bx; s_by[k][wq] = by;
        s_i0[k][wq] = y0c * WW + xl;
        s_i1[k][wq] = y1c * WW + xl;
    }
    __syncthreads();

    f32x4 acc[2][4];
#pragma unroll
    for (int mt = 0; mt < 2; ++mt)
#pragma unroll
        for (int nt = 0; nt < 4; ++nt) acc[mt][nt] = (f32x4){0.f, 0.f, 0.f, 0.f};

    const float* ub = u + (size_t)b * (CC * HH * WW);
    const bf16x8* afp = (const bf16x8*)af;

    for (int k = 0; k < 9; ++k) {
        {
            float ax = s_ax[k][lane], ay = s_ay[k][lane];
            float bx = s_bx[k][lane], by = s_by[k][lane];
            int   i0 = s_i0[k][lane], i1 = s_i1[k][lane];
#pragma unroll 4
            for (int g = 0; g < 4; ++g) {
                bf16x8 pk;
#pragma unroll
                for (int j = 0; j < 8; ++j) {
                    const float* up = ub + (size_t)(wv * 32 + g * 8 + j) * (HH * WW);
                    f32x2u r0 = *(const f32x2u*)(up + i0);
                    f32x2u r1 = *(const f32x2u*)(up + i1);
                    float v = ax * r0.x + ay * r0.y + bx * r1.x + by * r1.y;
                    pk[j] = (__bf16)v;
                }
                *(bf16x8*)&sampT[lane][wv * 32 + g * 8] = pk;
            }
        }
        __syncthreads();

#pragma unroll
        for (int ks = 0; ks < 4; ++ks) {
            bf16x8 a0 = afp[((k * 8 + wv * 2 + 0) * 4 + ks) * 64 + lane];
            bf16x8 a1 = afp[((k * 8 + wv * 2 + 1) * 4 + ks) * 64 + lane];
            int crow = ks * 32 + quad * 8;
#pragma unroll
            for (int nt = 0; nt < 4; ++nt) {
                bf16x8 bfrag = *(const bf16x8*)&sampT[nt * 16 + col][crow];
                acc[0][nt] = __builtin_amdgcn_mfma_f32_16x16x32_bf16(
                    a0, bfrag, acc[0][nt], 0, 0, 0);
                acc[1][nt] = __builtin_amdgcn_mfma_f32_16x16x32_bf16(
                    a1, bfrag, acc[1][nt], 0, 0, 0);
            }
        }
        __syncthreads();
    }

#pragma unroll
    for (int mt = 0; mt < 2; ++mt) {
#pragma unroll
        for (int r = 0; r < 4; ++r) {
            int o = wv * 32 + mt * 16 + quad * 4 + r;
            float bv = bias[o];
#pragma unroll
            for (int nt = 0; nt < 4; ++nt)
                out[((size_t)(b * CC + o) * HH + h) * WW + nt * 16 + col] =
                    acc[mt][nt][r] + bv;
        }
    }
}

extern "C" void kernel_launch(void* const* d_in, const int* in_sizes, int n_in,
                              void* d_out, int out_size, void* d_ws, size_t ws_size,
                              hipStream_t stream) {
    const float* x    = (const float*)d_in[0];
    const float* u    = (const float*)d_in[1];
    const float* wgt  = (const float*)d_in[2];
    const float* bias = (const float*)d_in[3];
    const float* ow   = (const float*)d_in[4];
    const float* ob   = (const float*)d_in[5];
    float* out = (float*)d_out;

    // Workspace layout (element-typed arithmetic only):
    float*  off = (float*)d_ws;                                  // 2,359,296 B
    __bf16* af  = (__bf16*)(off + (size_t)BB * NOFF * HH * WW);  //   294,912 B
    __bf16* waf = af + 147456;                                   //   147,456 B
    __bf16* ct  = waf + 73728;                                   // 16,777,216 B (fast path only)
    const size_t need_fast = 2359296 + 294912 + 147456 + (size_t)BB * HH * WW * 256 * 2;

    hipLaunchKernelGGL(prep_kernel, dim3(864), dim3(256), 0, stream,
                       wgt, ow, af, waf);

    if (ws_size >= need_fast) {
        hipLaunchKernelGGL(transpose_kernel, dim3(512), dim3(256), 0, stream,
                           x, u, ct);
        hipLaunchKernelGGL(offset_conv_fast_kernel, dim3(512), dim3(256), 0, stream,
                           ct, waf, ob, off);
        hipLaunchKernelGGL(fam_main_fast_kernel, dim3(512), dim3(256), 0, stream,
                           ct, af, bias, off, out);
    } else {
        hipLaunchKernelGGL(offset_conv_mfma_kernel, dim3(512), dim3(256), 0, stream,
                           x, u, waf, ob, off);
        hipLaunchKernelGGL(fam_main_kernel, dim3(512), dim3(256), 0, stream,
                           u, af, bias, off, out);
    }
}

// Round 7
// 129.803 us; speedup vs baseline: 4.0122x; 1.0579x over previous
//
#include <hip/hip_runtime.h>

#define BB 8
#define CC 128
#define HH 64
#define WW 64
#define NOFF 18

typedef __bf16 bf16x8 __attribute__((ext_vector_type(8)));
typedef float  f32x4  __attribute__((ext_vector_type(4)));
typedef float  f32x2u __attribute__((ext_vector_type(2), aligned(4)));

// ---------------------------------------------------------------------------
// Kernel 1: fused prep (weight->A-frag pack) + NCHW->NHWC transpose.
// Blocks [0,512): transpose ct[b][y][w][ic0..255] (bf16).
// Blocks [512,1376): pack af (main einsum) and waf (offset conv) A-frags.
// ---------------------------------------------------------------------------
__global__ __launch_bounds__(256) void prep_transpose_kernel(
    const float* __restrict__ x, const float* __restrict__ u,
    const float* __restrict__ w, const float* __restrict__ ow,
    __bf16* __restrict__ ct, __bf16* __restrict__ af, __bf16* __restrict__ waf)
{
    const int tid = threadIdx.x;
    if (blockIdx.x < 512) {
        const int id   = blockIdx.x;
        const int b    = id & 7;
        const int y    = id >> 3;
        const int lane = tid & 63;
        const int wv   = tid >> 6;

        __shared__ __align__(16) __bf16 t[64][264];
#pragma unroll
        for (int g = 0; g < 8; ++g) {
            bf16x8 pk;
#pragma unroll
            for (int j = 0; j < 8; ++j) {
                int ic = wv * 64 + g * 8 + j;
                float v = (ic < CC)
                    ? x[((size_t)(b * CC + ic) * HH + y) * WW + lane]
                    : u[((size_t)(b * CC + (ic - CC)) * HH + y) * WW + lane];
                pk[j] = (__bf16)v;
            }
            *(bf16x8*)&t[lane][wv * 64 + g * 8] = pk;
        }
        __syncthreads();

        __bf16* dst = ct + (size_t)(b * HH + y) * WW * 256;
#pragma unroll
        for (int p = 0; p < 8; ++p) {
            int idx = p * 256 + tid;
            int px = idx >> 5, ch = idx & 31;
            *(bf16x8*)(dst + px * 256 + ch * 8) = *(const bf16x8*)&t[px][ch * 8];
        }
    } else {
        int idx = (blockIdx.x - 512) * 256 + tid;
        if (idx < 147456) {
            int j    = idx & 7;
            int lane = (idx >> 3) & 63;
            int ks   = (idx >> 9) & 3;
            int mt2  = (idx >> 11) & 7;
            int k    = idx >> 14;
            int o = mt2 * 16 + (lane & 15);
            int c = ks * 32 + (lane >> 4) * 8 + j;
            af[idx] = (__bf16)w[(o * CC + c) * 9 + k];
        } else if (idx < 147456 + 73728) {
            int t2   = idx - 147456;
            int j    = t2 & 7;
            int lane = (t2 >> 3) & 63;
            int ks   = (t2 >> 9) & 7;
            int mt   = (t2 >> 12) & 1;
            int kk   = t2 >> 13;
            int oc = mt * 16 + (lane & 15);
            int ic = ks * 32 + (lane >> 4) * 8 + j;
            float v = (oc < NOFF) ? ow[(oc * 256 + ic) * 9 + kk] : 0.f;
            waf[t2] = (__bf16)v;
        }
    }
}

// ---------------------------------------------------------------------------
// Kernel 2: FUSED offset-conv + deformable sample + einsum. Block=(b,h).
//  Stage 1 (conv): stage ct rows -> T tile (LDS), MFMA vs waf -> off_lds.
//  Stage 2 (fam):  bilinear coeffs from off_lds; per tap: preloaded corner
//                  gathers (regs) -> weighted combine -> sampT[buf] -> MFMA.
//  Pipeline: preload(k+1) issued before the tap-k barrier; sampT double-
//  buffered -> ONE __syncthreads per tap; loads overlap MFMA + barrier.
//  LDS: union{ T 34848 B | sampT[2]+coeffs 48640 B } + off_lds 4608 B.
// ---------------------------------------------------------------------------
__global__ __launch_bounds__(256, 2) void fam_fused_kernel(
    const __bf16* __restrict__ ct, const __bf16* __restrict__ waf,
    const __bf16* __restrict__ af, const float* __restrict__ ob,
    const float* __restrict__ bias, float* __restrict__ out)
{
    const int id   = blockIdx.x;
    const int b    = id & 7;
    const int h    = id >> 3;
    const int tid  = threadIdx.x;
    const int lane = tid & 63;
    const int wv   = tid >> 6;
    const int col  = lane & 15;
    const int quad = lane >> 4;

    __shared__ __align__(16) unsigned char smem[48640];
    __shared__ float off_lds[NOFF][64];

    // conv view
    __bf16 (*T)[264] = (__bf16(*)[264])smem;               // 66 rows used
    // fam views (live after conv completes)
    __bf16 (*sampT)[64][136] = (__bf16(*)[64][136])smem;   // 2*64*136*2 = 34816 B
    float* s_ax = (float*)(smem + 34816);                  // 9*64 each
    float* s_ay = s_ax + 576;
    float* s_bx = s_ay + 576;
    float* s_by = s_bx + 576;
    int*   s_i0 = (int*)(s_by + 576);
    int*   s_i1 = s_i0 + 576;

    // ================= Stage 1: offset conv =================
    {
        T[0][tid]  = (__bf16)0.f;     // zero-pad rows (cols 0..255 used by MFMA)
        T[65][tid] = (__bf16)0.f;

        f32x4 acc0 = {0.f, 0.f, 0.f, 0.f};
        f32x4 acc1 = {0.f, 0.f, 0.f, 0.f};
        const bf16x8* wafp = (const bf16x8*)waf;

        for (int kh = 0; kh < 3; ++kh) {
            int y = h - 1 + kh;
            if (y < 0 || y >= HH) continue;       // block-uniform
            __syncthreads();
            const __bf16* row = ct + (size_t)(b * HH + y) * WW * 256;
#pragma unroll
            for (int p = 0; p < 8; ++p) {
                int idx = p * 256 + tid;
                int px = idx >> 5, ch = idx & 31;
                *(bf16x8*)&T[px + 1][ch * 8] =
                    *(const bf16x8*)(row + px * 256 + ch * 8);
            }
            __syncthreads();

#pragma unroll
            for (int kw = 0; kw < 3; ++kw) {
                int kk = kh * 3 + kw;
                const __bf16* brow = &T[wv * 16 + col + kw][quad * 8];
#pragma unroll
                for (int ks = 0; ks < 8; ++ks) {
                    bf16x8 bfrag = *(const bf16x8*)(brow + ks * 32);
                    bf16x8 a0 = wafp[((kk * 2 + 0) * 8 + ks) * 64 + lane];
                    bf16x8 a1 = wafp[((kk * 2 + 1) * 8 + ks) * 64 + lane];
                    acc0 = __builtin_amdgcn_mfma_f32_16x16x32_bf16(a0, bfrag, acc0, 0, 0, 0);
                    acc1 = __builtin_amdgcn_mfma_f32_16x16x32_bf16(a1, bfrag, acc1, 0, 0, 0);
                }
            }
        }

        int w2 = wv * 16 + col;
#pragma unroll
        for (int r = 0; r < 4; ++r)
            off_lds[quad * 4 + r][w2] = acc0[r] + ob[quad * 4 + r];
#pragma unroll
        for (int r = 0; r < 4; ++r) {
            int oc = 16 + quad * 4 + r;
            if (oc < NOFF) off_lds[oc][w2] = acc1[r] + ob[oc];
        }
    }
    __syncthreads();   // off_lds visible; T region dead

    // ================= Stage 2: bilinear coeffs =================
    for (int t = tid; t < 9 * 64; t += 256) {
        int k  = t >> 6;
        int wq = t & 63;
        float dy = off_lds[2 * k][wq];
        float dx = off_lds[2 * k + 1][wq];
        float py = (float)(h - 1 + k / 3) + dy;
        float px = (float)(wq - 1 + k % 3) + dx;
        float y0f = floorf(py), x0f = floorf(px);
        int y0 = (int)y0f, x0 = (int)x0f;
        float fy = py - y0f, fx = px - x0f;
        bool vy0 = (y0 >= 0) && (y0 < HH);
        bool vy1 = (y0 + 1 >= 0) && (y0 + 1 < HH);
        bool vx0 = (x0 >= 0) && (x0 < WW);
        bool vx1 = (x0 + 1 >= 0) && (x0 + 1 < WW);
        float w00 = (1.f - fy) * (1.f - fx) * ((vy0 && vx0) ? 1.f : 0.f);
        float w01 = (1.f - fy) * fx         * ((vy0 && vx1) ? 1.f : 0.f);
        float w10 = fy * (1.f - fx)         * ((vy1 && vx0) ? 1.f : 0.f);
        float w11 = fy * fx                 * ((vy1 && vx1) ? 1.f : 0.f);
        int y0c = min(max(y0, 0), HH - 1);
        int y1c = min(max(y0 + 1, 0), HH - 1);
        int x0c = min(max(x0, 0), WW - 1);
        int x1c = min(max(x0 + 1, 0), WW - 1);
        int xl  = min(max(x0, 0), WW - 2);
        float ax = ((x0c == xl)     ? w00 : 0.f) + ((x1c == xl)     ? w01 : 0.f);
        float ay = ((x0c == xl + 1) ? w00 : 0.f) + ((x1c == xl + 1) ? w01 : 0.f);
        float bx = ((x0c == xl)     ? w10 : 0.f) + ((x1c == xl)     ? w11 : 0.f);
        float by = ((x0c == xl + 1) ? w10 : 0.f) + ((x1c == xl + 1) ? w11 : 0.f);
        s_ax[k * 64 + wq] = ax; s_ay[k * 64 + wq] = ay;
        s_bx[k * 64 + wq] = bx; s_by[k * 64 + wq] = by;
        s_i0[k * 64 + wq] = y0c * WW + xl;
        s_i1[k * 64 + wq] = y1c * WW + xl;
    }
    __syncthreads();

    // ================= Stage 3: pipelined taps =================
    f32x4 acc[2][4];
#pragma unroll
    for (int mt = 0; mt < 2; ++mt)
#pragma unroll
        for (int nt = 0; nt < 4; ++nt) acc[mt][nt] = (f32x4){0.f, 0.f, 0.f, 0.f};

    const __bf16* ctb = ct + (size_t)b * (HH * WW * 256);
    const bf16x8* afp = (const bf16x8*)af;

    bf16x8 rA[4], rB[4], rC[4], rD[4];

    auto preload = [&](int kk) {
#pragma unroll
        for (int p = 0; p < 4; ++p) {
            int idx = p * 256 + tid;
            int px = idx >> 4, ch = idx & 15;
            const __bf16* r0 = ctb + (size_t)s_i0[kk * 64 + px] * 256 + 128 + ch * 8;
            const __bf16* r1 = ctb + (size_t)s_i1[kk * 64 + px] * 256 + 128 + ch * 8;
            rA[p] = *(const bf16x8*)r0;
            rB[p] = *(const bf16x8*)(r0 + 256);
            rC[p] = *(const bf16x8*)r1;
            rD[p] = *(const bf16x8*)(r1 + 256);
        }
    };
    auto combine = [&](int kk, int buf) {
#pragma unroll
        for (int p = 0; p < 4; ++p) {
            int idx = p * 256 + tid;
            int px = idx >> 4, ch = idx & 15;
            float ax = s_ax[kk * 64 + px], ay = s_ay[kk * 64 + px];
            float bx = s_bx[kk * 64 + px], by = s_by[kk * 64 + px];
            bf16x8 res;
#pragma unroll
            for (int j = 0; j < 8; ++j)
                res[j] = (__bf16)(ax * (float)rA[p][j] + ay * (float)rB[p][j] +
                                  bx * (float)rC[p][j] + by * (float)rD[p][j]);
            *(bf16x8*)&sampT[buf][px][ch * 8] = res;
        }
    };
    auto domfma = [&](int kk, int buf) {
#pragma unroll
        for (int ks = 0; ks < 4; ++ks) {
            bf16x8 a0 = afp[((kk * 8 + wv * 2 + 0) * 4 + ks) * 64 + lane];
            bf16x8 a1 = afp[((kk * 8 + wv * 2 + 1) * 4 + ks) * 64 + lane];
            int crow = ks * 32 + quad * 8;
#pragma unroll
            for (int nt = 0; nt < 4; ++nt) {
                bf16x8 bfrag = *(const bf16x8*)&sampT[buf][nt * 16 + col][crow];
                acc[0][nt] = __builtin_amdgcn_mfma_f32_16x16x32_bf16(
                    a0, bfrag, acc[0][nt], 0, 0, 0);
                acc[1][nt] = __builtin_amdgcn_mfma_f32_16x16x32_bf16(
                    a1, bfrag, acc[1][nt], 0, 0, 0);
            }
        }
    };

    preload(0);
    combine(0, 0);
    preload(1);
    __syncthreads();
    for (int k = 0; k < 9; ++k) {
        domfma(k, k & 1);
        if (k < 8) {
            combine(k + 1, (k + 1) & 1);
            if (k + 2 <= 8) preload(k + 2);
            __syncthreads();
        }
    }

    // ================= Epilogue =================
#pragma unroll
    for (int mt = 0; mt < 2; ++mt) {
#pragma unroll
        for (int r = 0; r < 4; ++r) {
            int o = wv * 32 + mt * 16 + quad * 4 + r;
            float bv = bias[o];
#pragma unroll
            for (int nt = 0; nt < 4; ++nt)
                out[((size_t)(b * CC + o) * HH + h) * WW + nt * 16 + col] =
                    acc[mt][nt][r] + bv;
        }
    }
}

// ===========================================================================
// Fallback path (proven R5 kernels; needs only 2.8 MB ws).
// ===========================================================================
__global__ __launch_bounds__(256) void prep_kernel(
    const float* __restrict__ w, const float* __restrict__ ow,
    __bf16* __restrict__ af, __bf16* __restrict__ waf)
{
    int idx = blockIdx.x * 256 + threadIdx.x;
    if (idx < 147456) {
        int j    = idx & 7;
        int lane = (idx >> 3) & 63;
        int ks   = (idx >> 9) & 3;
        int mt2  = (idx >> 11) & 7;
        int k    = idx >> 14;
        int o = mt2 * 16 + (lane & 15);
        int c = ks * 32 + (lane >> 4) * 8 + j;
        af[idx] = (__bf16)w[(o * CC + c) * 9 + k];
    } else if (idx < 147456 + 73728) {
        int t    = idx - 147456;
        int j    = t & 7;
        int lane = (t >> 3) & 63;
        int ks   = (t >> 9) & 7;
        int mt   = (t >> 12) & 1;
        int kk   = t >> 13;
        int oc = mt * 16 + (lane & 15);
        int ic = ks * 32 + (lane >> 4) * 8 + j;
        float v = (oc < NOFF) ? ow[(oc * 256 + ic) * 9 + kk] : 0.f;
        waf[t] = (__bf16)v;
    }
}

#define TS 264
__global__ __launch_bounds__(256) void offset_conv_mfma_kernel(
    const float* __restrict__ x, const float* __restrict__ u,
    const __bf16* __restrict__ waf, const float* __restrict__ ob,
    float* __restrict__ off)
{
    const int id   = blockIdx.x;
    const int b    = id & 7;
    const int h    = id >> 3;
    const int tid  = threadIdx.x;
    const int lane = tid & 63;
    const int wv   = tid >> 6;
    const int col  = lane & 15;
    const int quad = lane >> 4;

    __shared__ __align__(16) __bf16 T[66][TS];
    {
        T[0][tid]  = (__bf16)0.f;
        T[65][tid] = (__bf16)0.f;
    }

    f32x4 acc0 = {0.f, 0.f, 0.f, 0.f};
    f32x4 acc1 = {0.f, 0.f, 0.f, 0.f};
    const bf16x8* wafp = (const bf16x8*)waf;

    for (int kh = 0; kh < 3; ++kh) {
        int y = h - 1 + kh;
        if (y < 0 || y >= HH) continue;
        __syncthreads();
        {
            int w2 = lane;
#pragma unroll
            for (int g = 0; g < 8; ++g) {
                bf16x8 pk;
#pragma unroll
                for (int j = 0; j < 8; ++j) {
                    int ic = wv * 64 + g * 8 + j;
                    float v = (ic < CC)
                        ? x[((size_t)(b * CC + ic) * HH + y) * WW + w2]
                        : u[((size_t)(b * CC + (ic - CC)) * HH + y) * WW + w2];
                    pk[j] = (__bf16)v;
                }
                *(bf16x8*)&T[w2 + 1][wv * 64 + g * 8] = pk;
            }
        }
        __syncthreads();

#pragma unroll
        for (int kw = 0; kw < 3; ++kw) {
            int kk = kh * 3 + kw;
            const __bf16* brow = &T[wv * 16 + col + kw][quad * 8];
#pragma unroll
            for (int ks = 0; ks < 8; ++ks) {
                bf16x8 bfrag = *(const bf16x8*)(brow + ks * 32);
                bf16x8 a0 = wafp[((kk * 2 + 0) * 8 + ks) * 64 + lane];
                bf16x8 a1 = wafp[((kk * 2 + 1) * 8 + ks) * 64 + lane];
                acc0 = __builtin_amdgcn_mfma_f32_16x16x32_bf16(a0, bfrag, acc0, 0, 0, 0);
                acc1 = __builtin_amdgcn_mfma_f32_16x16x32_bf16(a1, bfrag, acc1, 0, 0, 0);
            }
        }
    }

    int w2 = wv * 16 + col;
#pragma unroll
    for (int r = 0; r < 4; ++r) {
        int oc = quad * 4 + r;
        off[((size_t)(b * NOFF + oc) * HH + h) * WW + w2] = acc0[r] + ob[oc];
    }
#pragma unroll
    for (int r = 0; r < 4; ++r) {
        int oc = 16 + quad * 4 + r;
        if (oc < NOFF)
            off[((size_t)(b * NOFF + oc) * HH + h) * WW + w2] = acc1[r] + ob[oc];
    }
}

__global__ __launch_bounds__(256) void fam_main_kernel(
    const float* __restrict__ u, const __bf16* __restrict__ af,
    const float* __restrict__ bias, const float* __restrict__ off,
    float* __restrict__ out)
{
    const int id   = blockIdx.x;
    const int b    = id & 7;
    const int h    = id >> 3;
    const int tid  = threadIdx.x;
    const int lane = tid & 63;
    const int wv   = tid >> 6;
    const int col  = lane & 15;
    const int quad = lane >> 4;

    __shared__ __align__(16) __bf16 sampT[64][136];
    __shared__ float s_ax[9][64], s_ay[9][64], s_bx[9][64], s_by[9][64];
    __shared__ int   s_i0[9][64], s_i1[9][64];

    for (int t = tid; t < 9 * 64; t += 256) {
        int k  = t >> 6;
        int wq = t & 63;
        float dy = off[((size_t)(b * NOFF + 2 * k)     * HH + h) * WW + wq];
        float dx = off[((size_t)(b * NOFF + 2 * k + 1) * HH + h) * WW + wq];
        float py = (float)(h - 1 + k / 3) + dy;
        float px = (float)(wq - 1 + k % 3) + dx;
        float y0f = floorf(py), x0f = floorf(px);
        int y0 = (int)y0f, x0 = (int)x0f;
        float fy = py - y0f, fx = px - x0f;
        bool vy0 = (y0 >= 0) && (y0 < HH);
        bool vy1 = (y0 + 1 >= 0) && (y0 + 1 < HH);
        bool vx0 = (x0 >= 0) && (x0 < WW);
        bool vx1 = (x0 + 1 >= 0) && (x0 + 1 < WW);
        float w00 = (1.f - fy) * (1.f - fx) * ((vy0 && vx0) ? 1.f : 0.f);
        float w01 = (1.f - fy) * fx         * ((vy0 && vx1) ? 1.f : 0.f);
        float w10 = fy * (1.f - fx)         * ((vy1 && vx0) ? 1.f : 0.f);
        float w11 = fy * fx                 * ((vy1 && vx1) ? 1.f : 0.f);
        int y0c = min(max(y0, 0), HH - 1);
        int y1c = min(max(y0 + 1, 0), HH - 1);
        int x0c = min(max(x0, 0), WW - 1);
        int x1c = min(max(x0 + 1, 0), WW - 1);
        int xl  = min(max(x0, 0), WW - 2);
        float ax = ((x0c == xl)     ? w00 : 0.f) + ((x1c == xl)     ? w01 : 0.f);
        float ay = ((x0c == xl + 1) ? w00 : 0.f) + ((x1c == xl + 1) ? w01 : 0.f);
        float bx = ((x0c == xl)     ? w10 : 0.f) + ((x1c == xl)     ? w11 : 0.f);
        float by = ((x0c == xl + 1) ? w10 : 0.f) + ((x1c == xl + 1) ? w11 : 0.f);
        s_ax[k][wq] = ax; s_ay[k][wq] = ay;
        s_bx[k][wq] = bx; s_by[k][wq] = by;
        s_i0[k][wq] = y0c * WW + xl;
        s_i1[k][wq] = y1c * WW + xl;
    }
    __syncthreads();

    f32x4 acc[2][4];
#pragma unroll
    for (int mt = 0; mt < 2; ++mt)
#pragma unroll
        for (int nt = 0; nt < 4; ++nt) acc[mt][nt] = (f32x4){0.f, 0.f, 0.f, 0.f};

    const float* ub = u + (size_t)b * (CC * HH * WW);
    const bf16x8* afp = (const bf16x8*)af;

    for (int k = 0; k < 9; ++k) {
        {
            float ax = s_ax[k][lane], ay = s_ay[k][lane];
            float bx = s_bx[k][lane], by = s_by[k][lane];
            int   i0 = s_i0[k][lane], i1 = s_i1[k][lane];
#pragma unroll 4
            for (int g = 0; g < 4; ++g) {
                bf16x8 pk;
#pragma unroll
                for (int j = 0; j < 8; ++j) {
                    const float* up = ub + (size_t)(wv * 32 + g * 8 + j) * (HH * WW);
                    f32x2u r0 = *(const f32x2u*)(up + i0);
                    f32x2u r1 = *(const f32x2u*)(up + i1);
                    float v = ax * r0.x + ay * r0.y + bx * r1.x + by * r1.y;
                    pk[j] = (__bf16)v;
                }
                *(bf16x8*)&sampT[lane][wv * 32 + g * 8] = pk;
            }
        }
        __syncthreads();

#pragma unroll
        for (int ks = 0; ks < 4; ++ks) {
            bf16x8 a0 = afp[((k * 8 + wv * 2 + 0) * 4 + ks) * 64 + lane];
            bf16x8 a1 = afp[((k * 8 + wv * 2 + 1) * 4 + ks) * 64 + lane];
            int crow = ks * 32 + quad * 8;
#pragma unroll
            for (int nt = 0; nt < 4; ++nt) {
                bf16x8 bfrag = *(const bf16x8*)&sampT[nt * 16 + col][crow];
                acc[0][nt] = __builtin_amdgcn_mfma_f32_16x16x32_bf16(
                    a0, bfrag, acc[0][nt], 0, 0, 0);
                acc[1][nt] = __builtin_amdgcn_mfma_f32_16x16x32_bf16(
                    a1, bfrag, acc[1][nt], 0, 0, 0);
            }
        }
        __syncthreads();
    }

#pragma unroll
    for (int mt = 0; mt < 2; ++mt) {
#pragma unroll
        for (int r = 0; r < 4; ++r) {
            int o = wv * 32 + mt * 16 + quad * 4 + r;
            float bv = bias[o];
#pragma unroll
            for (int nt = 0; nt < 4; ++nt)
                out[((size_t)(b * CC + o) * HH + h) * WW + nt * 16 + col] =
                    acc[mt][nt][r] + bv;
        }
    }
}

extern "C" void kernel_launch(void* const* d_in, const int* in_sizes, int n_in,
                              void* d_out, int out_size, void* d_ws, size_t ws_size,
                              hipStream_t stream) {
    const float* x    = (const float*)d_in[0];
    const float* u    = (const float*)d_in[1];
    const float* wgt  = (const float*)d_in[2];
    const float* bias = (const float*)d_in[3];
    const float* ow   = (const float*)d_in[4];
    const float* ob   = (const float*)d_in[5];
    float* out = (float*)d_out;

    // Workspace layout (element-typed arithmetic only):
    float*  off = (float*)d_ws;                                  // 2,359,296 B (fallback only)
    __bf16* af  = (__bf16*)(off + (size_t)BB * NOFF * HH * WW);  //   294,912 B
    __bf16* waf = af + 147456;                                   //   147,456 B
    __bf16* ct  = waf + 73728;                                   // 16,777,216 B (fast path)
    const size_t need_fast = 2359296 + 294912 + 147456 + (size_t)BB * HH * WW * 256 * 2;

    if (ws_size >= need_fast) {
        hipLaunchKernelGGL(prep_transpose_kernel, dim3(1376), dim3(256), 0, stream,
                           x, u, wgt, ow, ct, af, waf);
        hipLaunchKernelGGL(fam_fused_kernel, dim3(512), dim3(256), 0, stream,
                           ct, waf, af, ob, bias, out);
    } else {
        hipLaunchKernelGGL(prep_kernel, dim3(864), dim3(256), 0, stream,
                           wgt, ow, af, waf);
        hipLaunchKernelGGL(offset_conv_mfma_kernel, dim3(512), dim3(256), 0, stream,
                           x, u, waf, ob, off);
        hipLaunchKernelGGL(fam_main_kernel, dim3(512), dim3(256), 0, stream,
                           u, af, bias, off, out);
    }
}